// Round 9
// baseline (192.254 us; speedup 1.0000x reference)
//
#include <hip/hip_runtime.h>

#define R_DIM 1024
#define N_DIM 1024
#define FEAT  1024
#define EMB   64
#define GROUP 16
#define DG    64

typedef _Float16 half8  __attribute__((ext_vector_type(8)));
typedef _Float16 half4v __attribute__((ext_vector_type(4)));
typedef float    f32x4  __attribute__((ext_vector_type(4)));

__device__ __forceinline__ half8 cvt8(const float* p) {
  const float4 a = *(const float4*)p;
  const float4 b = *(const float4*)(p + 4);
  half8 h;
  h[0] = (_Float16)a.x; h[1] = (_Float16)a.y; h[2] = (_Float16)a.z; h[3] = (_Float16)a.w;
  h[4] = (_Float16)b.x; h[5] = (_Float16)b.y; h[6] = (_Float16)b.z; h[7] = (_Float16)b.w;
  return h;
}
__device__ __forceinline__ half8 cvt8v(float4 a, float4 b) {
  half8 h;
  h[0] = (_Float16)a.x; h[1] = (_Float16)a.y; h[2] = (_Float16)a.z; h[3] = (_Float16)a.w;
  h[4] = (_Float16)b.x; h[5] = (_Float16)b.y; h[6] = (_Float16)b.z; h[7] = (_Float16)b.w;
  return h;
}

// ---------------------------------------------------------------------------
// K1: qhI/khI both stored 8-interleaved [g][e>>3][row][e&7] so attn fragment
// loads (A=k, B=q after the swap) are lane-coalesced 256B segments.
// ---------------------------------------------------------------------------
__global__ __launch_bounds__(256) void qk_gemm(
    const float* __restrict__ roi, const float* __restrict__ Wq,
    const float* __restrict__ bq,  const float* __restrict__ Wk,
    const float* __restrict__ bk,  _Float16* __restrict__ qhI,
    _Float16* __restrict__ khI)
{
  __shared__ float aT[16][68];
  __shared__ float bqT[16][68];
  __shared__ float bkT[16][68];
  const int t  = threadIdx.x;
  const int r0 = blockIdx.x * 64, c0 = blockIdx.y * 64;
  const int lr = t >> 2, lk = (t & 3) << 2;
  const int ty = t >> 4, tx = t & 15;
  const float* ap  = roi + (r0 + lr) * FEAT + lk;
  const float* bqp = Wq  + (c0 + lr) * FEAT + lk;
  const float* bkp = Wk  + (c0 + lr) * FEAT + lk;
  float4 av  = *(const float4*)ap;
  float4 bqv = *(const float4*)bqp;
  float4 bkv = *(const float4*)bkp;
  float accq[4][4] = {}, acck[4][4] = {};
  for (int k0 = 0; k0 < FEAT; k0 += 16) {
    aT[lk+0][lr]=av.x;   aT[lk+1][lr]=av.y;   aT[lk+2][lr]=av.z;   aT[lk+3][lr]=av.w;
    bqT[lk+0][lr]=bqv.x; bqT[lk+1][lr]=bqv.y; bqT[lk+2][lr]=bqv.z; bqT[lk+3][lr]=bqv.w;
    bkT[lk+0][lr]=bkv.x; bkT[lk+1][lr]=bkv.y; bkT[lk+2][lr]=bkv.z; bkT[lk+3][lr]=bkv.w;
    __syncthreads();
    const bool more = (k0 + 16) < FEAT;
    float4 av_n, bqv_n, bkv_n;
    if (more) {
      av_n  = *(const float4*)(ap  + k0 + 16);
      bqv_n = *(const float4*)(bqp + k0 + 16);
      bkv_n = *(const float4*)(bkp + k0 + 16);
    }
#pragma unroll
    for (int kk = 0; kk < 16; ++kk) {
      const float4 a4 = *(const float4*)&aT[kk][ty << 2];
      const float4 q4 = *(const float4*)&bqT[kk][tx << 2];
      const float4 k4 = *(const float4*)&bkT[kk][tx << 2];
      const float ar[4] = {a4.x, a4.y, a4.z, a4.w};
      const float qr[4] = {q4.x, q4.y, q4.z, q4.w};
      const float kr[4] = {k4.x, k4.y, k4.z, k4.w};
#pragma unroll
      for (int i = 0; i < 4; ++i)
#pragma unroll
        for (int j = 0; j < 4; ++j) {
          accq[i][j] += ar[i] * qr[j];
          acck[i][j] += ar[i] * kr[j];
        }
    }
    __syncthreads();
    if (more) { av = av_n; bqv = bqv_n; bkv = bkv_n; }
  }
  const float4 bq4 = *(const float4*)(bq + c0 + (tx << 2));
  const float4 bk4 = *(const float4*)(bk + c0 + (tx << 2));
  const float bqr[4] = {bq4.x, bq4.y, bq4.z, bq4.w};
  const float bkr[4] = {bk4.x, bk4.y, bk4.z, bk4.w};
  const int g = c0 >> 6;            // e = tx*4+j within this g's 64-chunk
#pragma unroll
  for (int i = 0; i < 4; ++i) {
    half4v oq, ok;
#pragma unroll
    for (int j = 0; j < 4; ++j) {
      oq[j] = (_Float16)(accq[i][j] + bqr[j]);
      ok[j] = (_Float16)(acck[i][j] + bkr[j]);
    }
    const int row = r0 + (ty << 2) + i;
    const size_t idx = ((((size_t)g << 3) + (tx >> 1)) << 13) + ((size_t)row << 3) + ((tx & 1) << 2);
    *(half4v*)(qhI + idx) = oq;
    *(half4v*)(khI + idx) = ok;
  }
}

// ---------------------------------------------------------------------------
// K2 v5: pos MFMA with ZERO LDS / ZERO barriers (R8 lesson: every LDS-staged
// variant stalled at ~2.4 TB/s; models say the barrier-phased duty cycle is
// the only uncounted cost). A-fragment loaded straight from global in
// fragment order (lane(q16,q4): row tile*16+q16, 32B contiguous at e=q4*8);
// MFMA performs the transpose; D-layout (4 consecutive n per lane) gives
// vectorized 8B logw stores. 8 tiles/wave, register prefetch of tile t+1.
// ---------------------------------------------------------------------------
__global__ __launch_bounds__(256) void pos_mfma(
    const float* __restrict__ pe, const float* __restrict__ Wp,
    const float* __restrict__ bp, _Float16* __restrict__ logw)
{
  const int t = threadIdx.x;
  const int w = t >> 6, l = t & 63, q16 = l & 15, q4 = l >> 4;
  const float* wpp = Wp + (q16 << 6) + (q4 << 3);
  const half8 wb0 = cvt8(wpp);
  const half8 wb1 = cvt8(wpp + 32);
  const float bpg = bp[q16];

  int tile = ((blockIdx.x << 2) + w) << 3;          // 8 tiles of 16 rows/wave
  const float* src = pe + ((size_t)tile << 10) + (q16 << 6) + (q4 << 3);
  float4 c0 = *(const float4*)(src);
  float4 c1 = *(const float4*)(src + 4);
  float4 c2 = *(const float4*)(src + 32);
  float4 c3 = *(const float4*)(src + 36);
  for (int it = 0; it < 8; ++it, ++tile) {
    float4 n0 = c0, n1 = c1, n2 = c2, n3 = c3;
    if (it < 7) {
      const float* s2 = src + ((size_t)(it + 1) << 10);
      n0 = *(const float4*)(s2);
      n1 = *(const float4*)(s2 + 4);
      n2 = *(const float4*)(s2 + 32);
      n3 = *(const float4*)(s2 + 36);
    }
    const half8 a0 = cvt8v(c0, c1);                 // e = q4*8 + [0..7]
    const half8 a1 = cvt8v(c2, c3);                 // e = 32 + q4*8 + [0..7]
    f32x4 acc = (f32x4){0.f, 0.f, 0.f, 0.f};
    acc = __builtin_amdgcn_mfma_f32_16x16x32_f16(a0, wb0, acc, 0, 0, 0);
    acc = __builtin_amdgcn_mfma_f32_16x16x32_f16(a1, wb1, acc, 0, 0, 0);
    half4v o;
#pragma unroll
    for (int j = 0; j < 4; ++j)
      o[j] = (_Float16)__logf(fmaxf(acc[j] + bpg, 1e-6f));
    // D: col=q16 -> g ; row=q4*4+j -> 4 consecutive n within the tile
    const int r  = tile >> 6;
    const int nb = ((tile & 63) << 4) + (q4 << 2);
    *(half4v*)(logw + ((((size_t)r << 4) + q16) << 10) + nb) = o;
    c0 = n0; c1 = n1; c2 = n2; c3 = n3;
  }
}

// ---------------------------------------------------------------------------
// K3: kc stored 8-interleaved: kctI[g][n>>3][o][n&7]  (lane-coalesced PV B).
// ---------------------------------------------------------------------------
__global__ __launch_bounds__(256) void kc_gemm(
    const float* __restrict__ roi, const float* __restrict__ Wc,
    _Float16* __restrict__ kctI)
{
  __shared__ float aT[16][68];
  __shared__ float bT[16][68];
  const int t   = threadIdx.x;
  const int n0g = blockIdx.x * 64;
  const int g   = blockIdx.y;
  const int lr = t >> 2, lk = (t & 3) << 2;
  const int ty = t >> 4, tx = t & 15;
  const float* ap  = Wc  + (size_t)(g * DG + lr) * FEAT + lk;
  const float* bp_ = roi + (size_t)(n0g + lr) * FEAT + lk;
  float4 av = *(const float4*)ap;
  float4 bv = *(const float4*)bp_;
  float acc[4][4] = {};
  for (int k0 = 0; k0 < FEAT; k0 += 16) {
    aT[lk+0][lr]=av.x; aT[lk+1][lr]=av.y; aT[lk+2][lr]=av.z; aT[lk+3][lr]=av.w;
    bT[lk+0][lr]=bv.x; bT[lk+1][lr]=bv.y; bT[lk+2][lr]=bv.z; bT[lk+3][lr]=bv.w;
    __syncthreads();
    const bool more = (k0 + 16) < FEAT;
    float4 av_n, bv_n;
    if (more) {
      av_n = *(const float4*)(ap  + k0 + 16);
      bv_n = *(const float4*)(bp_ + k0 + 16);
    }
#pragma unroll
    for (int kk = 0; kk < 16; ++kk) {
      const float4 a4 = *(const float4*)&aT[kk][ty << 2];
      const float4 b4 = *(const float4*)&bT[kk][tx << 2];
      const float ar[4] = {a4.x, a4.y, a4.z, a4.w};
      const float br[4] = {b4.x, b4.y, b4.z, b4.w};
#pragma unroll
      for (int i = 0; i < 4; ++i)
#pragma unroll
        for (int j = 0; j < 4; ++j) acc[i][j] += ar[i] * br[j];
    }
    __syncthreads();
    if (more) { av = av_n; bv = bv_n; }
  }
#pragma unroll
  for (int i = 0; i < 4; ++i) {
    half4v o4;
#pragma unroll
    for (int j = 0; j < 4; ++j) o4[j] = (_Float16)acc[i][j];
    *(half4v*)(kctI + ((((size_t)g << 7) + ((n0g + (tx << 2)) >> 3)) << 9)
               + (((ty << 2) + i) << 3) + ((tx & 1) << 2)) = o4;
  }
}

// ---------------------------------------------------------------------------
// K4 v4: swapped QK^T (S^T = mfma(K, Q)) so each lane owns row r=q16 with 4
// consecutive n per register: logw -> 16x 8B vector loads (was 64 scalar),
// P -> 16x 8B ds_writes (was 64 scalar), row-reduce = 2 shfl_xor (16,32).
// Q fragment hoisted (one load from interleaved qhI). PV unchanged.
// ---------------------------------------------------------------------------
#define PLD 1032
__global__ __launch_bounds__(256) void attn_mfma(
    const _Float16* __restrict__ qhI, const _Float16* __restrict__ khI,
    const _Float16* __restrict__ logw, const _Float16* __restrict__ kctI,
    const float* __restrict__ bc, float* __restrict__ outp)
{
  __shared__ float Ored[4][16][68];
  __shared__ float redm[4][16];
  __shared__ float redl[4][16];
  __shared__ __align__(16) _Float16 P[16][PLD];

  const int t   = threadIdx.x;
  const int w   = t >> 6;
  const int l   = t & 63;
  const int q16 = l & 15;
  const int q4  = l >> 4;
  const int bid = blockIdx.x;
  const int g   = (bid & 7) + ((bid >> 9) << 3);
  const int r0  = ((bid >> 3) & 63) << 4;
  const int nbase = w << 8;

  const _Float16* kbase = khI  + ((size_t)g << 16);
  const _Float16* qbase = qhI  + ((size_t)g << 16);
  const _Float16* cbase = kctI + ((size_t)g << 16);

  // B-fragment: q rows (col = q16 -> r), hoisted across all 16 tiles
  const half8 b0 = *(const half8*)(qbase + ((size_t)q4 << 13) + ((r0 + q16) << 3));
  const half8 b1 = *(const half8*)(qbase + ((size_t)(4 + q4) << 13) + ((r0 + q16) << 3));

  f32x4 S[16];
#pragma unroll
  for (int i = 0; i < 16; ++i) S[i] = (f32x4){0.f, 0.f, 0.f, 0.f};
#pragma unroll
  for (int t16 = 0; t16 < 16; ++t16) {
    const int n = nbase + (t16 << 4) + q16;       // A row -> n
    const half8 k0 = *(const half8*)(kbase + ((size_t)q4 << 13) + (n << 3));
    const half8 k1 = *(const half8*)(kbase + ((size_t)(4 + q4) << 13) + (n << 3));
    S[t16] = __builtin_amdgcn_mfma_f32_16x16x32_f16(k0, b0, S[t16], 0, 0, 0);
    S[t16] = __builtin_amdgcn_mfma_f32_16x16x32_f16(k1, b1, S[t16], 0, 0, 0);
  }
  // lane holds S^T: r = r0+q16 fixed, n = nbase + t16*16 + q4*4 + j
  const _Float16* lwp = logw + ((((size_t)(r0 + q16)) << 4) + (size_t)g) * 1024;
#pragma unroll
  for (int t16 = 0; t16 < 16; ++t16) {
    const half4v lw = *(const half4v*)(lwp + nbase + (t16 << 4) + (q4 << 2));
#pragma unroll
    for (int j = 0; j < 4; ++j)
      S[t16][j] = S[t16][j] * 0.125f + (float)lw[j];
  }

  // row max: in-lane over 64 regs, then across q4 (xor 16,32), then waves
  float m = -1e30f;
#pragma unroll
  for (int t16 = 0; t16 < 16; ++t16)
#pragma unroll
    for (int j = 0; j < 4; ++j) m = fmaxf(m, S[t16][j]);
  m = fmaxf(m, __shfl_xor(m, 16));
  m = fmaxf(m, __shfl_xor(m, 32));
  if (q4 == 0) redm[w][q16] = m;
  __syncthreads();
  m = fmaxf(fmaxf(redm[0][q16], redm[1][q16]), fmaxf(redm[2][q16], redm[3][q16]));

  // exp + vectorized P writes + row sum
  float ls = 0.f;
#pragma unroll
  for (int t16 = 0; t16 < 16; ++t16) {
    half4v pv;
#pragma unroll
    for (int j = 0; j < 4; ++j) {
      const float p = __expf(S[t16][j] - m);
      ls += p;
      pv[j] = (_Float16)p;
    }
    *(half4v*)&P[q16][nbase + (t16 << 4) + (q4 << 2)] = pv;
  }
  ls += __shfl_xor(ls, 16);
  ls += __shfl_xor(ls, 32);
  if (q4 == 0) redl[w][q16] = ls;
  __syncthreads();

  // PV: unchanged (A = P rows by q16, B = kctI interleaved)
  f32x4 O[4];
#pragma unroll
  for (int ot = 0; ot < 4; ++ot) O[ot] = (f32x4){0.f, 0.f, 0.f, 0.f};
#pragma unroll
  for (int ks = 0; ks < 8; ++ks) {
    const int nk = nbase + (ks << 5) + (q4 << 3);
    const half8 pa = *(const half8*)&P[q16][nk];
#pragma unroll
    for (int ot = 0; ot < 4; ++ot) {
      const half8 bfr = *(const half8*)(cbase + ((size_t)(nk >> 3) << 9) + (((ot << 4) + q16) << 3));
      O[ot] = __builtin_amdgcn_mfma_f32_16x16x32_f16(pa, bfr, O[ot], 0, 0, 0);
    }
  }
#pragma unroll
  for (int ot = 0; ot < 4; ++ot)
#pragma unroll
    for (int j = 0; j < 4; ++j)
      Ored[w][(q4 << 2) + j][(ot << 4) + q16] = O[ot][j];
  __syncthreads();

  const int r  = t >> 4;
  const int o0 = (t & 15) << 2;
  const float lsum = redl[0][r] + redl[1][r] + redl[2][r] + redl[3][r];
  const float inv  = 1.0f / lsum;
  float o[4];
#pragma unroll
  for (int c = 0; c < 4; ++c)
    o[c] = Ored[0][r][o0 + c] + Ored[1][r][o0 + c] + Ored[2][r][o0 + c] + Ored[3][r][o0 + c];
  const float4 bcv = *(const float4*)(bc + (g << 6) + o0);
  float4 res;
  res.x = o[0] * inv + bcv.x;
  res.y = o[1] * inv + bcv.y;
  res.z = o[2] * inv + bcv.z;
  res.w = o[3] * inv + bcv.w;
  *(float4*)(outp + (size_t)(r0 + r) * FEAT + (g << 6) + o0) = res;
}

// ---------------------------------------------------------------------------
extern "C" void kernel_launch(void* const* d_in, const int* in_sizes, int n_in,
                              void* d_out, int out_size, void* d_ws, size_t ws_size,
                              hipStream_t stream)
{
  const float* pe  = (const float*)d_in[0];
  const float* roi = (const float*)d_in[1];
  const float* Wq  = (const float*)d_in[2];
  const float* bq  = (const float*)d_in[3];
  const float* Wk  = (const float*)d_in[4];
  const float* bk  = (const float*)d_in[5];
  const float* Wp  = (const float*)d_in[6];
  const float* bp  = (const float*)d_in[7];
  const float* Wc  = (const float*)d_in[8];
  const float* bc  = (const float*)d_in[9];
  float* outp = (float*)d_out;

  char* ws = (char*)d_ws;
  _Float16* qhI  = (_Float16*)(ws);                        // 2 MB [g][e/8][r][e%8]
  _Float16* khI  = (_Float16*)(ws + ((size_t)2 << 20));    // 2 MB [g][e/8][n][e%8]
  _Float16* kctI = (_Float16*)(ws + ((size_t)4 << 20));    // 2 MB [g][n/8][o][n%8]
  _Float16* logw = (_Float16*)(ws + ((size_t)6 << 20));    // 32 MB (total 38 MB)

  qk_gemm<<<dim3(16, 16), 256, 0, stream>>>(roi, Wq, bq, Wk, bk, qhI, khI);
  pos_mfma<<<2048, 256, 0, stream>>>(pe, Wp, bp, logw);
  kc_gemm<<<dim3(16, 16), 256, 0, stream>>>(roi, Wc, kctI);
  attn_mfma<<<1024, 256, 0, stream>>>(qhI, khI, logw, kctI, bc, outp);
}

// Round 10
// 190.730 us; speedup vs baseline: 1.0080x; 1.0080x over previous
//
#include <hip/hip_runtime.h>

#define R_DIM 1024
#define N_DIM 1024
#define FEAT  1024
#define EMB   64
#define GROUP 16
#define DG    64

typedef _Float16 half8  __attribute__((ext_vector_type(8)));
typedef _Float16 half4v __attribute__((ext_vector_type(4)));
typedef float    f32x4  __attribute__((ext_vector_type(4)));

__device__ __forceinline__ half8 cvt8(const float* p) {
  const float4 a = *(const float4*)p;
  const float4 b = *(const float4*)(p + 4);
  half8 h;
  h[0] = (_Float16)a.x; h[1] = (_Float16)a.y; h[2] = (_Float16)a.z; h[3] = (_Float16)a.w;
  h[4] = (_Float16)b.x; h[5] = (_Float16)b.y; h[6] = (_Float16)b.z; h[7] = (_Float16)b.w;
  return h;
}
__device__ __forceinline__ half8 cvt8v(float4 a, float4 b) {
  half8 h;
  h[0] = (_Float16)a.x; h[1] = (_Float16)a.y; h[2] = (_Float16)a.z; h[3] = (_Float16)a.w;
  h[4] = (_Float16)b.x; h[5] = (_Float16)b.y; h[6] = (_Float16)b.z; h[7] = (_Float16)b.w;
  return h;
}

// ---------------------------------------------------------------------------
// K1: qhI/khI stored 8-interleaved [g][e>>3][row][e&7] so attn fragment loads
// (A=k, B=q after the swap) are lane-coalesced 256B segments.
// ---------------------------------------------------------------------------
__global__ __launch_bounds__(256) void qk_gemm(
    const float* __restrict__ roi, const float* __restrict__ Wq,
    const float* __restrict__ bq,  const float* __restrict__ Wk,
    const float* __restrict__ bk,  _Float16* __restrict__ qhI,
    _Float16* __restrict__ khI)
{
  __shared__ float aT[16][68];
  __shared__ float bqT[16][68];
  __shared__ float bkT[16][68];
  const int t  = threadIdx.x;
  const int r0 = blockIdx.x * 64, c0 = blockIdx.y * 64;
  const int lr = t >> 2, lk = (t & 3) << 2;
  const int ty = t >> 4, tx = t & 15;
  const float* ap  = roi + (r0 + lr) * FEAT + lk;
  const float* bqp = Wq  + (c0 + lr) * FEAT + lk;
  const float* bkp = Wk  + (c0 + lr) * FEAT + lk;
  float4 av  = *(const float4*)ap;
  float4 bqv = *(const float4*)bqp;
  float4 bkv = *(const float4*)bkp;
  float accq[4][4] = {}, acck[4][4] = {};
  for (int k0 = 0; k0 < FEAT; k0 += 16) {
    aT[lk+0][lr]=av.x;   aT[lk+1][lr]=av.y;   aT[lk+2][lr]=av.z;   aT[lk+3][lr]=av.w;
    bqT[lk+0][lr]=bqv.x; bqT[lk+1][lr]=bqv.y; bqT[lk+2][lr]=bqv.z; bqT[lk+3][lr]=bqv.w;
    bkT[lk+0][lr]=bkv.x; bkT[lk+1][lr]=bkv.y; bkT[lk+2][lr]=bkv.z; bkT[lk+3][lr]=bkv.w;
    __syncthreads();
    const bool more = (k0 + 16) < FEAT;
    float4 av_n, bqv_n, bkv_n;
    if (more) {
      av_n  = *(const float4*)(ap  + k0 + 16);
      bqv_n = *(const float4*)(bqp + k0 + 16);
      bkv_n = *(const float4*)(bkp + k0 + 16);
    }
#pragma unroll
    for (int kk = 0; kk < 16; ++kk) {
      const float4 a4 = *(const float4*)&aT[kk][ty << 2];
      const float4 q4 = *(const float4*)&bqT[kk][tx << 2];
      const float4 k4 = *(const float4*)&bkT[kk][tx << 2];
      const float ar[4] = {a4.x, a4.y, a4.z, a4.w};
      const float qr[4] = {q4.x, q4.y, q4.z, q4.w};
      const float kr[4] = {k4.x, k4.y, k4.z, k4.w};
#pragma unroll
      for (int i = 0; i < 4; ++i)
#pragma unroll
        for (int j = 0; j < 4; ++j) {
          accq[i][j] += ar[i] * qr[j];
          acck[i][j] += ar[i] * kr[j];
        }
    }
    __syncthreads();
    if (more) { av = av_n; bqv = bqv_n; bkv = bkv_n; }
  }
  const float4 bq4 = *(const float4*)(bq + c0 + (tx << 2));
  const float4 bk4 = *(const float4*)(bk + c0 + (tx << 2));
  const float bqr[4] = {bq4.x, bq4.y, bq4.z, bq4.w};
  const float bkr[4] = {bk4.x, bk4.y, bk4.z, bk4.w};
  const int g = c0 >> 6;
#pragma unroll
  for (int i = 0; i < 4; ++i) {
    half4v oq, ok;
#pragma unroll
    for (int j = 0; j < 4; ++j) {
      oq[j] = (_Float16)(accq[i][j] + bqr[j]);
      ok[j] = (_Float16)(acck[i][j] + bkr[j]);
    }
    const int row = r0 + (ty << 2) + i;
    const size_t idx = ((((size_t)g << 3) + (tx >> 1)) << 13) + ((size_t)row << 3) + ((tx & 1) << 2);
    *(half4v*)(qhI + idx) = oq;
    *(half4v*)(khI + idx) = ok;
  }
}

// ---------------------------------------------------------------------------
// K2 v6: zero-barrier MFMA pos. 4 tiles/wave, ALL 16 tile-loads issued up
// front (no intra-wave serial chain); D-fragments staged through a per-wave
// LDS tile (same-wave lgkmcnt only, no __syncthreads) and stored as full
// 64B lines (v5 stored 16 scattered 32B chunks/instr -> write-allocate tax).
// ---------------------------------------------------------------------------
__global__ __launch_bounds__(256) void pos_mfma(
    const float* __restrict__ pe, const float* __restrict__ Wp,
    const float* __restrict__ bp, _Float16* __restrict__ logw)
{
  __shared__ __align__(16) _Float16 SW[4][16][72];   // 9.2 KB, per-wave tiles
  const int t = threadIdx.x;
  const int w = t >> 6, l = t & 63, q16 = l & 15, q4 = l >> 4;
  const float* wpp = Wp + (q16 << 6) + (q4 << 3);
  const half8 wb0 = cvt8(wpp);
  const half8 wb1 = cvt8(wpp + 32);
  const float bpg = bp[q16];

  const int tile0 = (blockIdx.x << 4) + (w << 2);    // 4 tiles of 16 rows/wave
  const float* src = pe + ((size_t)tile0 << 10) + (q16 << 6) + (q4 << 3);

  // issue all 16 loads up front (independent; TLP + 16KB/wave in flight)
  float4 c[16];
#pragma unroll
  for (int it = 0; it < 4; ++it) {
    const float* s = src + ((size_t)it << 10);
    c[it * 4 + 0] = *(const float4*)(s);
    c[it * 4 + 1] = *(const float4*)(s + 4);
    c[it * 4 + 2] = *(const float4*)(s + 32);
    c[it * 4 + 3] = *(const float4*)(s + 36);
  }
#pragma unroll
  for (int it = 0; it < 4; ++it) {
    const half8 a0 = cvt8v(c[it * 4 + 0], c[it * 4 + 1]);
    const half8 a1 = cvt8v(c[it * 4 + 2], c[it * 4 + 3]);
    f32x4 acc = (f32x4){0.f, 0.f, 0.f, 0.f};
    acc = __builtin_amdgcn_mfma_f32_16x16x32_f16(a0, wb0, acc, 0, 0, 0);
    acc = __builtin_amdgcn_mfma_f32_16x16x32_f16(a1, wb1, acc, 0, 0, 0);
    half4v o;
#pragma unroll
    for (int j = 0; j < 4; ++j)
      o[j] = (_Float16)__logf(fmaxf(acc[j] + bpg, 1e-6f));
    // D: col=q16 -> g ; row=q4*4+j -> n offset (it*16 + q4*4 + j)
    *(half4v*)&SW[w][q16][(it << 4) + (q4 << 2)] = o;
  }
  __builtin_amdgcn_s_waitcnt(0);            // lgkmcnt(0): same-wave LDS visible
  // coalesced out: lane -> g=l>>2, 32B chunk c=l&3 of the 128B g-row
  const int gg = l >> 2, cc = l & 3;
  const int r  = tile0 >> 6;
  const int n0 = ((tile0 & 63) << 4) + (cc << 4);
  _Float16* dst = logw + ((((size_t)r << 4) + gg) << 10) + n0;
  const half8 v0 = *(const half8*)&SW[w][gg][cc << 4];
  const half8 v1 = *(const half8*)&SW[w][gg][(cc << 4) + 8];
  *(half8*)(dst)     = v0;
  *(half8*)(dst + 8) = v1;
}

// ---------------------------------------------------------------------------
// K3: kc stored 8-interleaved: kctI[g][n>>3][o][n&7]  (lane-coalesced PV B).
// ---------------------------------------------------------------------------
__global__ __launch_bounds__(256) void kc_gemm(
    const float* __restrict__ roi, const float* __restrict__ Wc,
    _Float16* __restrict__ kctI)
{
  __shared__ float aT[16][68];
  __shared__ float bT[16][68];
  const int t   = threadIdx.x;
  const int n0g = blockIdx.x * 64;
  const int g   = blockIdx.y;
  const int lr = t >> 2, lk = (t & 3) << 2;
  const int ty = t >> 4, tx = t & 15;
  const float* ap  = Wc  + (size_t)(g * DG + lr) * FEAT + lk;
  const float* bp_ = roi + (size_t)(n0g + lr) * FEAT + lk;
  float4 av = *(const float4*)ap;
  float4 bv = *(const float4*)bp_;
  float acc[4][4] = {};
  for (int k0 = 0; k0 < FEAT; k0 += 16) {
    aT[lk+0][lr]=av.x; aT[lk+1][lr]=av.y; aT[lk+2][lr]=av.z; aT[lk+3][lr]=av.w;
    bT[lk+0][lr]=bv.x; bT[lk+1][lr]=bv.y; bT[lk+2][lr]=bv.z; bT[lk+3][lr]=bv.w;
    __syncthreads();
    const bool more = (k0 + 16) < FEAT;
    float4 av_n, bv_n;
    if (more) {
      av_n = *(const float4*)(ap  + k0 + 16);
      bv_n = *(const float4*)(bp_ + k0 + 16);
    }
#pragma unroll
    for (int kk = 0; kk < 16; ++kk) {
      const float4 a4 = *(const float4*)&aT[kk][ty << 2];
      const float4 b4 = *(const float4*)&bT[kk][tx << 2];
      const float ar[4] = {a4.x, a4.y, a4.z, a4.w};
      const float br[4] = {b4.x, b4.y, b4.z, b4.w};
#pragma unroll
      for (int i = 0; i < 4; ++i)
#pragma unroll
        for (int j = 0; j < 4; ++j) acc[i][j] += ar[i] * br[j];
    }
    __syncthreads();
    if (more) { av = av_n; bv = bv_n; }
  }
#pragma unroll
  for (int i = 0; i < 4; ++i) {
    half4v o4;
#pragma unroll
    for (int j = 0; j < 4; ++j) o4[j] = (_Float16)acc[i][j];
    *(half4v*)(kctI + ((((size_t)g << 7) + ((n0g + (tx << 2)) >> 3)) << 9)
               + (((ty << 2) + i) << 3) + ((tx & 1) << 2)) = o4;
  }
}

// ---------------------------------------------------------------------------
// K4 v5: swapped QK^T, interleaved operands — GRID REVERTED to natural 2D
// dim3(64,16) (R7's manual XCD swizzle is the prime regression suspect;
// R4 measured 67us with natural dispatch order).
// ---------------------------------------------------------------------------
#define PLD 1032
__global__ __launch_bounds__(256) void attn_mfma(
    const _Float16* __restrict__ qhI, const _Float16* __restrict__ khI,
    const _Float16* __restrict__ logw, const _Float16* __restrict__ kctI,
    const float* __restrict__ bc, float* __restrict__ outp)
{
  __shared__ float Ored[4][16][68];
  __shared__ float redm[4][16];
  __shared__ float redl[4][16];
  __shared__ __align__(16) _Float16 P[16][PLD];

  const int t   = threadIdx.x;
  const int w   = t >> 6;
  const int l   = t & 63;
  const int q16 = l & 15;
  const int q4  = l >> 4;
  const int g   = blockIdx.y;
  const int r0  = blockIdx.x << 4;
  const int nbase = w << 8;

  const _Float16* kbase = khI  + ((size_t)g << 16);
  const _Float16* qbase = qhI  + ((size_t)g << 16);
  const _Float16* cbase = kctI + ((size_t)g << 16);

  // B-fragment: q rows (col = q16 -> r), hoisted across all 16 tiles
  const half8 b0 = *(const half8*)(qbase + ((size_t)q4 << 13) + ((r0 + q16) << 3));
  const half8 b1 = *(const half8*)(qbase + ((size_t)(4 + q4) << 13) + ((r0 + q16) << 3));

  f32x4 S[16];
#pragma unroll
  for (int i = 0; i < 16; ++i) S[i] = (f32x4){0.f, 0.f, 0.f, 0.f};
#pragma unroll
  for (int t16 = 0; t16 < 16; ++t16) {
    const int n = nbase + (t16 << 4) + q16;       // A row -> n
    const half8 k0 = *(const half8*)(kbase + ((size_t)q4 << 13) + (n << 3));
    const half8 k1 = *(const half8*)(kbase + ((size_t)(4 + q4) << 13) + (n << 3));
    S[t16] = __builtin_amdgcn_mfma_f32_16x16x32_f16(k0, b0, S[t16], 0, 0, 0);
    S[t16] = __builtin_amdgcn_mfma_f32_16x16x32_f16(k1, b1, S[t16], 0, 0, 0);
  }
  // lane holds S^T: r = r0+q16 fixed, n = nbase + t16*16 + q4*4 + j
  const _Float16* lwp = logw + ((((size_t)(r0 + q16)) << 4) + (size_t)g) * 1024;
#pragma unroll
  for (int t16 = 0; t16 < 16; ++t16) {
    const half4v lw = *(const half4v*)(lwp + nbase + (t16 << 4) + (q4 << 2));
#pragma unroll
    for (int j = 0; j < 4; ++j)
      S[t16][j] = S[t16][j] * 0.125f + (float)lw[j];
  }

  // row max: in-lane, then across q4 (xor 16,32), then waves
  float m = -1e30f;
#pragma unroll
  for (int t16 = 0; t16 < 16; ++t16)
#pragma unroll
    for (int j = 0; j < 4; ++j) m = fmaxf(m, S[t16][j]);
  m = fmaxf(m, __shfl_xor(m, 16));
  m = fmaxf(m, __shfl_xor(m, 32));
  if (q4 == 0) redm[w][q16] = m;
  __syncthreads();
  m = fmaxf(fmaxf(redm[0][q16], redm[1][q16]), fmaxf(redm[2][q16], redm[3][q16]));

  // exp + vectorized P writes + row sum
  float ls = 0.f;
#pragma unroll
  for (int t16 = 0; t16 < 16; ++t16) {
    half4v pv;
#pragma unroll
    for (int j = 0; j < 4; ++j) {
      const float p = __expf(S[t16][j] - m);
      ls += p;
      pv[j] = (_Float16)p;
    }
    *(half4v*)&P[q16][nbase + (t16 << 4) + (q4 << 2)] = pv;
  }
  ls += __shfl_xor(ls, 16);
  ls += __shfl_xor(ls, 32);
  if (q4 == 0) redl[w][q16] = ls;
  __syncthreads();

  // PV: A = P rows by q16, B = kctI interleaved
  f32x4 O[4];
#pragma unroll
  for (int ot = 0; ot < 4; ++ot) O[ot] = (f32x4){0.f, 0.f, 0.f, 0.f};
#pragma unroll
  for (int ks = 0; ks < 8; ++ks) {
    const int nk = nbase + (ks << 5) + (q4 << 3);
    const half8 pa = *(const half8*)&P[q16][nk];
#pragma unroll
    for (int ot = 0; ot < 4; ++ot) {
      const half8 bfr = *(const half8*)(cbase + ((size_t)(nk >> 3) << 9) + (((ot << 4) + q16) << 3));
      O[ot] = __builtin_amdgcn_mfma_f32_16x16x32_f16(pa, bfr, O[ot], 0, 0, 0);
    }
  }
#pragma unroll
  for (int ot = 0; ot < 4; ++ot)
#pragma unroll
    for (int j = 0; j < 4; ++j)
      Ored[w][(q4 << 2) + j][(ot << 4) + q16] = O[ot][j];
  __syncthreads();

  const int r  = t >> 4;
  const int o0 = (t & 15) << 2;
  const float lsum = redl[0][r] + redl[1][r] + redl[2][r] + redl[3][r];
  const float inv  = 1.0f / lsum;
  float o[4];
#pragma unroll
  for (int c = 0; c < 4; ++c)
    o[c] = Ored[0][r][o0 + c] + Ored[1][r][o0 + c] + Ored[2][r][o0 + c] + Ored[3][r][o0 + c];
  const float4 bcv = *(const float4*)(bc + (g << 6) + o0);
  float4 res;
  res.x = o[0] * inv + bcv.x;
  res.y = o[1] * inv + bcv.y;
  res.z = o[2] * inv + bcv.z;
  res.w = o[3] * inv + bcv.w;
  *(float4*)(outp + (size_t)(r0 + r) * FEAT + (g << 6) + o0) = res;
}

// ---------------------------------------------------------------------------
extern "C" void kernel_launch(void* const* d_in, const int* in_sizes, int n_in,
                              void* d_out, int out_size, void* d_ws, size_t ws_size,
                              hipStream_t stream)
{
  const float* pe  = (const float*)d_in[0];
  const float* roi = (const float*)d_in[1];
  const float* Wq  = (const float*)d_in[2];
  const float* bq  = (const float*)d_in[3];
  const float* Wk  = (const float*)d_in[4];
  const float* bk  = (const float*)d_in[5];
  const float* Wp  = (const float*)d_in[6];
  const float* bp  = (const float*)d_in[7];
  const float* Wc  = (const float*)d_in[8];
  const float* bc  = (const float*)d_in[9];
  float* outp = (float*)d_out;

  char* ws = (char*)d_ws;
  _Float16* qhI  = (_Float16*)(ws);                        // 2 MB [g][e/8][r][e%8]
  _Float16* khI  = (_Float16*)(ws + ((size_t)2 << 20));    // 2 MB [g][e/8][n][e%8]
  _Float16* kctI = (_Float16*)(ws + ((size_t)4 << 20));    // 2 MB [g][n/8][o][n%8]
  _Float16* logw = (_Float16*)(ws + ((size_t)6 << 20));    // 32 MB (total 38 MB)

  qk_gemm<<<dim3(16, 16), 256, 0, stream>>>(roi, Wq, bq, Wk, bk, qhI, khI);
  pos_mfma<<<4096, 256, 0, stream>>>(pe, Wp, bp, logw);
  kc_gemm<<<dim3(16, 16), 256, 0, stream>>>(roi, Wc, kctI);
  attn_mfma<<<dim3(64, 16), 256, 0, stream>>>(qhI, khI, logw, kctI, bc, outp);
}